// Round 1
// baseline (456.753 us; speedup 1.0000x reference)
//
#include <hip/hip_runtime.h>

// DynamicVoxelizer: B=8, N=1e6, C=4 fp32 points -> 5 concatenated outputs
// (points_out[B,N,4], voxel_coords[B,N,3], point_idxes[B,N],
//  point_offsets[B,N,3], valid[B,N]) all written as float values into d_out.
//
// VOXEL_SIZE = (0.1, 0.1, 0.2); PC_RANGE = (-51.2,-51.2,-5.0, 51.2,51.2,3.0)
// grid = (1024, 1024, 40)

#define NPTS 1000000  // N (points per batch) — fixed by the problem

struct F3 { float x, y, z; };  // 12B contiguous per-lane store (coalesced)

__global__ __launch_bounds__(256) void voxelize_kernel(
    const float4* __restrict__ pts, float* __restrict__ out, int total) {
  int i = blockIdx.x * blockDim.x + threadIdx.x;
  if (i >= total) return;

  float4 p = pts[i];

  // not_nan over all 4 channels
  bool has_nan = (p.x != p.x) | (p.y != p.y) | (p.z != p.z) | (p.w != p.w);

  // cf = floor((xyz - pmin) / vs)  — IEEE fp32 sub + correctly-rounded div,
  // matching numpy's op-for-op rounding (critical: a 1-voxel flip breaks
  // point_offsets tolerance).
  float fx = floorf((p.x - (-51.2f)) / 0.1f);
  float fy = floorf((p.y - (-51.2f)) / 0.1f);
  float fz = floorf((p.z - (-5.0f))  / 0.2f);
  int cx = (int)fx, cy = (int)fy, cz = (int)fz;

  bool in_range = (cx >= 0) & (cx < 1024) &
                  (cy >= 0) & (cy < 1024) &
                  (cz >= 0) & (cz < 40);
  bool valid = (!has_nan) && in_range;

  // centers = cf*vs + pmin + vs*0.5 ; offsets = xyz - centers
  // (any fp-contract ULP noise here is ~4e-6 << 1e-3 threshold)
  float ox = p.x - (fx * 0.1f + (-51.2f) + 0.05f);
  float oy = p.y - (fy * 0.1f + (-51.2f) + 0.05f);
  float oz = p.z - (fz * 0.2f + (-5.0f)  + 0.1f);

  long long t = total;
  float*  pout = out;                          // [total*4]
  F3*     vox  = (F3*)(out + 4 * t);           // [total*3] as z,y,x
  float*  idx  = out + 7 * t;                  // [total]
  F3*     poff = (F3*)(out + 8 * t);           // [total*3]
  float*  pval = out + 11 * t;                 // [total]

  float4 po;
  if (valid) { po = p; } else { po.x = po.y = po.z = po.w = 0.0f; }
  ((float4*)pout)[i] = po;

  F3 vc, of;
  if (valid) {
    vc.x = (float)cz; vc.y = (float)cy; vc.z = (float)cx;  // reversed (z,y,x)
    of.x = ox; of.y = oy; of.z = oz;
  } else {
    vc.x = vc.y = vc.z = -1.0f;
    of.x = of.y = of.z = 0.0f;
  }
  vox[i]  = vc;
  poff[i] = of;

  idx[i]  = valid ? (float)(i % NPTS) : -1.0f;  // arange(N) per batch
  pval[i] = valid ? 1.0f : 0.0f;
}

extern "C" void kernel_launch(void* const* d_in, const int* in_sizes, int n_in,
                              void* d_out, int out_size, void* d_ws, size_t ws_size,
                              hipStream_t stream) {
  (void)n_in; (void)d_ws; (void)ws_size; (void)out_size;
  const float4* pts = (const float4*)d_in[0];
  float* out = (float*)d_out;
  int total = in_sizes[0] / 4;  // B*N = 8,000,000
  int block = 256;
  int grid = (total + block - 1) / block;
  voxelize_kernel<<<grid, block, 0, stream>>>(pts, out, total);
}

// Round 3
// 443.489 us; speedup vs baseline: 1.0299x; 1.0299x over previous
//
#include <hip/hip_runtime.h>

// DynamicVoxelizer: B=8, N=1e6, C=4 fp32 points -> 5 concatenated outputs
// (points_out[B,N,4], voxel_coords[B,N,3], point_idxes[B,N],
//  point_offsets[B,N,3], valid[B,N]) written as float values into d_out.
//
// R1/R2: stage the 3-wide / scalar outputs through LDS so every global store
// is a lane-contiguous nontemporal dwordx4 (12B/lane struct stores held write
// BW to ~3 TB/s). NT builtins need native clang vectors, not HIP float4.

#define NPTS 1000000  // N (points per batch) — fixed by the problem
#define BLK 256

typedef float f4 __attribute__((ext_vector_type(4)));  // NT-builtin-compatible

__global__ __launch_bounds__(BLK) void voxelize_kernel(
    const f4* __restrict__ pts, float* __restrict__ out, int total) {
  __shared__ __align__(16) float s_vox[BLK * 3];   // z,y,x per point
  __shared__ __align__(16) float s_poff[BLK * 3];
  __shared__ __align__(16) float s_misc[BLK * 2];  // idx[256] | val[256]

  const int tid  = threadIdx.x;
  const int base = blockIdx.x * BLK;      // full blocks only (total % 256 == 0)
  const int i    = base + tid;

  f4 p = __builtin_nontemporal_load(&pts[i]);

  bool has_nan = (p.x != p.x) | (p.y != p.y) | (p.z != p.z) | (p.w != p.w);

  // cf = floor((xyz - pmin) / vs) — IEEE sub + correctly-rounded div to match
  // numpy op-for-op (a 1-voxel flip breaks the point_offsets tolerance).
  float fx = floorf((p.x - (-51.2f)) / 0.1f);
  float fy = floorf((p.y - (-51.2f)) / 0.1f);
  float fz = floorf((p.z - (-5.0f))  / 0.2f);
  int cx = (int)fx, cy = (int)fy, cz = (int)fz;

  bool in_range = (cx >= 0) & (cx < 1024) &
                  (cy >= 0) & (cy < 1024) &
                  (cz >= 0) & (cz < 40);
  bool valid = (!has_nan) && in_range;

  float ox = p.x - (fx * 0.1f + (-51.2f) + 0.05f);
  float oy = p.y - (fy * 0.1f + (-51.2f) + 0.05f);
  float oz = p.z - (fz * 0.2f + (-5.0f)  + 0.1f);

  // points_out: already 16B/lane contiguous — store direct.
  f4 po = valid ? p : (f4){0.0f, 0.0f, 0.0f, 0.0f};
  __builtin_nontemporal_store(po, &((f4*)out)[i]);

  // Stage 3-wide + scalar outputs in LDS (stride-3 dword writes = 2-way = free).
  if (valid) {
    s_vox[tid * 3 + 0] = (float)cz;   // reversed (z,y,x)
    s_vox[tid * 3 + 1] = (float)cy;
    s_vox[tid * 3 + 2] = (float)cx;
    s_poff[tid * 3 + 0] = ox;
    s_poff[tid * 3 + 1] = oy;
    s_poff[tid * 3 + 2] = oz;
    s_misc[tid]       = (float)(i % NPTS);  // arange(N) per batch
    s_misc[BLK + tid] = 1.0f;
  } else {
    s_vox[tid * 3 + 0] = -1.0f;
    s_vox[tid * 3 + 1] = -1.0f;
    s_vox[tid * 3 + 2] = -1.0f;
    s_poff[tid * 3 + 0] = 0.0f;
    s_poff[tid * 3 + 1] = 0.0f;
    s_poff[tid * 3 + 2] = 0.0f;
    s_misc[tid]       = -1.0f;
    s_misc[BLK + tid] = 0.0f;
  }
  __syncthreads();

  const long long t = total;
  // Region base offsets (floats): all 16B-aligned for t = 8e6, base % 256 == 0.
  f4* gvox  = (f4*)(out + 4 * t  + (long long)base * 3);  // 192 float4
  f4* gpoff = (f4*)(out + 8 * t  + (long long)base * 3);  // 192 float4
  f4* gidx  = (f4*)(out + 7 * t  + base);                 // 64 float4
  f4* gval  = (f4*)(out + 11 * t + base);                 // 64 float4

  const f4* v4 = (const f4*)s_vox;   // 192 entries, 16B/lane reads
  const f4* o4 = (const f4*)s_poff;
  const f4* m4 = (const f4*)s_misc;  // 128 entries

  if (tid < 192) {
    __builtin_nontemporal_store(v4[tid], &gvox[tid]);
    __builtin_nontemporal_store(o4[tid], &gpoff[tid]);
  } else {
    int j = tid - 192;                       // 64 threads cover idx + val
    __builtin_nontemporal_store(m4[j],      &gidx[j]);
    __builtin_nontemporal_store(m4[64 + j], &gval[j]);
  }
}

// Scalar tail path for total % 256 != 0 (unused at B*N = 8e6, kept for safety).
__global__ __launch_bounds__(64) void voxelize_tail(
    const float* __restrict__ ptsf, float* __restrict__ out, int total, int start) {
  int i = start + blockIdx.x * blockDim.x + threadIdx.x;
  if (i >= total) return;
  float px = ptsf[i * 4 + 0], py = ptsf[i * 4 + 1];
  float pz = ptsf[i * 4 + 2], pw = ptsf[i * 4 + 3];
  bool has_nan = (px != px) | (py != py) | (pz != pz) | (pw != pw);
  float fx = floorf((px - (-51.2f)) / 0.1f);
  float fy = floorf((py - (-51.2f)) / 0.1f);
  float fz = floorf((pz - (-5.0f))  / 0.2f);
  int cx = (int)fx, cy = (int)fy, cz = (int)fz;
  bool in_range = (cx >= 0) & (cx < 1024) & (cy >= 0) & (cy < 1024) &
                  (cz >= 0) & (cz < 40);
  bool valid = (!has_nan) && in_range;
  float ox = px - (fx * 0.1f + (-51.2f) + 0.05f);
  float oy = py - (fy * 0.1f + (-51.2f) + 0.05f);
  float oz = pz - (fz * 0.2f + (-5.0f)  + 0.1f);
  long long t = total;
  out[i * 4 + 0] = valid ? px : 0.0f;
  out[i * 4 + 1] = valid ? py : 0.0f;
  out[i * 4 + 2] = valid ? pz : 0.0f;
  out[i * 4 + 3] = valid ? pw : 0.0f;
  float* vox  = out + 4 * t  + (long long)i * 3;
  float* poff = out + 8 * t  + (long long)i * 3;
  if (valid) {
    vox[0] = (float)cz; vox[1] = (float)cy; vox[2] = (float)cx;
    poff[0] = ox; poff[1] = oy; poff[2] = oz;
    out[7 * t + i]  = (float)(i % NPTS);
    out[11 * t + i] = 1.0f;
  } else {
    vox[0] = -1.0f; vox[1] = -1.0f; vox[2] = -1.0f;
    poff[0] = 0.0f; poff[1] = 0.0f; poff[2] = 0.0f;
    out[7 * t + i]  = -1.0f;
    out[11 * t + i] = 0.0f;
  }
}

extern "C" void kernel_launch(void* const* d_in, const int* in_sizes, int n_in,
                              void* d_out, int out_size, void* d_ws, size_t ws_size,
                              hipStream_t stream) {
  (void)n_in; (void)d_ws; (void)ws_size; (void)out_size;
  const f4* pts = (const f4*)d_in[0];
  float* out = (float*)d_out;
  int total = in_sizes[0] / 4;  // B*N = 8,000,000
  int full_blocks = total / BLK;
  if (full_blocks > 0)
    voxelize_kernel<<<full_blocks, BLK, 0, stream>>>(pts, out, total);
  int rem = total - full_blocks * BLK;
  if (rem > 0)
    voxelize_tail<<<(rem + 63) / 64, 64, 0, stream>>>((const float*)d_in[0], out,
                                                      total, full_blocks * BLK);
}